// Round 5
// baseline (177.502 us; speedup 1.0000x reference)
//
#include <hip/hip_runtime.h>

// Chamfer (bidirectional 1-NN mean of squared distances), two [16384,3] fp32 clouds.
// d(i,j) = |a_i|^2 + (|b_j|^2 - 2 a_i.b_j); row-min taken on t(j)=|b_j|^2-2a.b_j.
//
// Round-5: MPTS=8 spills ~32 floats/thread no matter what (R3/R4: VGPR=36,
// +16/+32MB scratch in WRITE_SIZE, issue rate collapsed). Revert to MPTS=4
// (R1: VGPR=24, clean codegen) and keep the cheap wins:
//  - B-pair + v_min3_f32 merge: 3.5 VALU instr/pair (vs R1's 4.0).
//  - CHUNK=256 -> 2048 blocks = 8 blocks/CU = 8 waves/SIMD (R1 had 4): hides the
//    broadcast-ds_read lgkmcnt stalls that held R1 at ~55% true VALU issue.
//  - Fused last-block reduce (1 memset + 1 kernel).

#define NPTS 16384
#define CHUNK 256
#define NCHUNKS (NPTS / CHUNK)          // 64
#define MPTS 4                          // A-points per thread
#define BLOCK 256
#define APT (BLOCK * MPTS)              // 1024 A-points per block
#define NATILES (NPTS / APT)            // 16
#define NBLOCKS (NATILES * NCHUNKS * 2) // 2048
#define CINIT 0x7F7F7F7Fu

__global__ __launch_bounds__(BLOCK) void chamfer_fused(
    const float* __restrict__ P0, const float* __restrict__ P1,
    unsigned* __restrict__ dmin_all, unsigned* __restrict__ counter,
    float* __restrict__ out)
{
    const float* A;
    const float* B;
    unsigned* dmin;
    if (blockIdx.z == 0) { A = P0; B = P1; dmin = dmin_all; }
    else                 { A = P1; B = P0; dmin = dmin_all + NPTS; }

    __shared__ float4 sB[CHUNK];   // {-2bx, -2by, -2bz, |b|^2} per B-point

    const int tid = threadIdx.x;

    // Stage this B-chunk into LDS, pre-transformed (one point per thread).
    {
        const int j0 = (blockIdx.y * CHUNK + tid) * 3;
        const float bx = B[j0 + 0];
        const float by = B[j0 + 1];
        const float bz = B[j0 + 2];
        sB[tid] = make_float4(-2.0f * bx, -2.0f * by, -2.0f * bz,
                              bx * bx + by * by + bz * bz);
    }
    __syncthreads();

    // 4 A-points per thread (R1-class register pressure; no spill).
    float ax[MPTS], ay[MPTS], az[MPTS], a2[MPTS], tmin[MPTS];
    const int ibase = blockIdx.x * APT + tid * MPTS;
#pragma unroll
    for (int m = 0; m < MPTS; ++m) {
        ax[m] = A[(ibase + m) * 3 + 0];
        ay[m] = A[(ibase + m) * 3 + 1];
        az[m] = A[(ibase + m) * 3 + 2];
        a2[m] = ax[m] * ax[m] + ay[m] * ay[m] + az[m] * az[m];
        tmin[m] = 3.0e38f;
    }

    // Inner loop: 2 broadcast ds_read_b128 per B-pair, then per A-point:
    // 6 v_fma_f32 + 1 v_min3_f32 = 3.5 VALU instr per pair (1:14 LDS:VALU instr).
#pragma unroll 4
    for (int q = 0; q < CHUNK / 2; ++q) {
        const float4 b0 = sB[2 * q];
        const float4 b1 = sB[2 * q + 1];
#pragma unroll
        for (int m = 0; m < MPTS; ++m) {
            float t0 = fmaf(az[m], b0.z, b0.w);
            t0 = fmaf(ay[m], b0.y, t0);
            t0 = fmaf(ax[m], b0.x, t0);
            float t1 = fmaf(az[m], b1.z, b1.w);
            t1 = fmaf(ay[m], b1.y, t1);
            t1 = fmaf(ax[m], b1.x, t1);
            tmin[m] = fminf(fminf(t0, t1), tmin[m]);   // -> v_min3_f32
        }
    }

    // Merge partial mins across chunks (d >= 0 after clamp -> uint order == float order).
#pragma unroll
    for (int m = 0; m < MPTS; ++m) {
        const float d = fmaxf(tmin[m] + a2[m], 0.0f);
        atomicMin(&dmin[ibase + m], __float_as_uint(d));
    }

    // ---- last-block-reduces ----
    __threadfence();
    __syncthreads();
    __shared__ unsigned s_old;
    if (tid == 0) s_old = atomicAdd(counter, 1u);
    __syncthreads();
    if (s_old != CINIT + (unsigned)NBLOCKS - 1u) return;

    __threadfence();
    double s = 0.0;
    for (int i = tid; i < 2 * NPTS; i += BLOCK) {
        const unsigned bits = __hip_atomic_load(&dmin_all[i], __ATOMIC_RELAXED,
                                                __HIP_MEMORY_SCOPE_AGENT);
        s += (double)__uint_as_float(bits);
    }
    __shared__ double sd[BLOCK];
    sd[tid] = s;
    __syncthreads();
    for (int off = BLOCK / 2; off > 0; off >>= 1) {
        if (tid < off) sd[tid] += sd[tid + off];
        __syncthreads();
    }
    // mean(dist0) + mean(dist1) = (sum0 + sum1) / NPTS  (N0 == N1)
    if (tid == 0) out[0] = (float)(sd[0] / (double)NPTS);
}

extern "C" void kernel_launch(void* const* d_in, const int* in_sizes, int n_in,
                              void* d_out, int out_size, void* d_ws, size_t ws_size,
                              hipStream_t stream)
{
    const float* P0 = (const float*)d_in[0];
    const float* P1 = (const float*)d_in[1];
    float* out = (float*)d_out;
    unsigned* dmin = (unsigned*)d_ws;            // 2*NPTS partial mins
    unsigned* counter = dmin + 2 * NPTS;         // arrival counter (starts at 0x7F7F7F7F)

    // One memset covers dmin init (0x7F7F7F7F = 3.39e38 > any dist) AND the counter
    // (counts up from 0x7F7F7F7F; last block sees CINIT + NBLOCKS - 1).
    hipMemsetAsync(dmin, 0x7F, (size_t)(2 * NPTS + 1) * sizeof(unsigned), stream);

    dim3 grid(NATILES, NCHUNKS, 2);   // 16 x 64 x 2 = 2048 blocks
    chamfer_fused<<<grid, BLOCK, 0, stream>>>(P0, P1, dmin, counter, out);
}

// Round 6
// 81.059 us; speedup vs baseline: 2.1898x; 2.1898x over previous
//
#include <hip/hip_runtime.h>

// Chamfer (bidirectional 1-NN mean of squared distances), two [16384,3] fp32 clouds.
// d(i,j) = |a_i|^2 + (|b_j|^2 - 2 a_i.b_j); row-min taken on t(j)=|b_j|^2-2a.b_j.
//
// Round-6: R1 skeleton (separate reduce, NO fused tail — the per-block serialized
// counter atomic was the R2-R5 poison: time scaled with block count, not inner loop).
// Single structural change vs R1: B-side moved off the LDS pipe. R1 was co-saturated
// by the broadcast ds_read_b128 return path (1KB/instr to RF ~ 8 cyc = its VALU cost).
// Now both clouds are pre-transformed to float4 {-2x,-2y,-2z,|p|^2} and the inner
// loop reads B via wave-uniform loads -> s_load_dwordx4 (SMEM pipe, SGPR operands).
// No LDS, no __syncthreads. 3.75 VALU instr/pair (6 fma + 1 min3 per A per B-pair).

#define NPTS 16384
#define CHUNK 512
#define NCHUNKS (NPTS / CHUNK)   // 32
#define MPTS 4                   // A-points per thread
#define BLOCK 256
#define APT (BLOCK * MPTS)       // 1024 A-points per block
#define NATILES (NPTS / APT)     // 16

// Pre-transform both clouds: Pt[i] = {-2x, -2y, -2z, |p|^2}. i in [0, 2*NPTS).
__global__ __launch_bounds__(256) void prep_kernel(
    const float* __restrict__ P0, const float* __restrict__ P1,
    float4* __restrict__ Pt)
{
    const int i = blockIdx.x * 256 + threadIdx.x;
    const float* P = (i < NPTS) ? P0 : P1;
    const int k = (i < NPTS) ? i : i - NPTS;
    const float x = P[k * 3 + 0], y = P[k * 3 + 1], z = P[k * 3 + 2];
    Pt[i] = make_float4(-2.f * x, -2.f * y, -2.f * z, x * x + y * y + z * z);
}

__global__ __launch_bounds__(BLOCK) void chamfer_min_kernel(
    const float4* __restrict__ Pt, unsigned* __restrict__ dmin_all)
{
    const float4* Arole;
    const float4* Brole;
    unsigned* dmin;
    if (blockIdx.z == 0) { Arole = Pt;        Brole = Pt + NPTS; dmin = dmin_all; }
    else                 { Arole = Pt + NPTS; Brole = Pt;        dmin = dmin_all + NPTS; }

    const int tid = threadIdx.x;
    const int ibase = blockIdx.x * APT + tid * MPTS;

    // A-points: recover raw coords from the transformed array (x = -0.5 * (-2x)),
    // |a|^2 comes free in .w. 12 one-time muls per thread.
    float ax[MPTS], ay[MPTS], az[MPTS], a2[MPTS], tmin[MPTS];
#pragma unroll
    for (int m = 0; m < MPTS; ++m) {
        const float4 av = Arole[ibase + m];
        ax[m] = -0.5f * av.x;
        ay[m] = -0.5f * av.y;
        az[m] = -0.5f * av.z;
        a2[m] = av.w;
        tmin[m] = 3.0e38f;
    }

    // Inner loop: b0/b1 addresses are wave-uniform (loop counter + block offset only)
    // -> compiler scalarizes to s_load_dwordx4; b components are SGPR operands to the
    // fmas (1 SGPR read per VALU instr; .w needs one v_mov each). Per 2 B-points:
    // 2 mov + 24 fma + 4 min3 = 30 VALU, zero LDS.
    const float4* __restrict__ Bc = Brole + blockIdx.y * CHUNK;
#pragma unroll 4
    for (int q = 0; q < CHUNK / 2; ++q) {
        const float4 b0 = Bc[2 * q];
        const float4 b1 = Bc[2 * q + 1];
#pragma unroll
        for (int m = 0; m < MPTS; ++m) {
            float t0 = fmaf(az[m], b0.z, b0.w);
            t0 = fmaf(ay[m], b0.y, t0);
            t0 = fmaf(ax[m], b0.x, t0);
            float t1 = fmaf(az[m], b1.z, b1.w);
            t1 = fmaf(ay[m], b1.y, t1);
            t1 = fmaf(ax[m], b1.x, t1);
            tmin[m] = fminf(fminf(t0, t1), tmin[m]);   // -> v_min3_f32
        }
    }

    // Merge partial mins across chunks (d >= 0 after clamp -> uint order == float order).
#pragma unroll
    for (int m = 0; m < MPTS; ++m) {
        const float d = fmaxf(tmin[m] + a2[m], 0.0f);
        atomicMin(&dmin[ibase + m], __float_as_uint(d));
    }
}

__global__ __launch_bounds__(1024) void chamfer_reduce_kernel(
    const unsigned* __restrict__ dmin_all, float* __restrict__ out)
{
    __shared__ double sdata[1024];
    double s = 0.0;
    for (int i = threadIdx.x; i < 2 * NPTS; i += 1024)
        s += (double)__uint_as_float(dmin_all[i]);
    sdata[threadIdx.x] = s;
    __syncthreads();
    for (int off = 512; off > 0; off >>= 1) {
        if (threadIdx.x < off) sdata[threadIdx.x] += sdata[threadIdx.x + off];
        __syncthreads();
    }
    // mean(dist0) + mean(dist1) = (sum0 + sum1) / NPTS  (N0 == N1)
    if (threadIdx.x == 0) out[0] = (float)(sdata[0] / (double)NPTS);
}

extern "C" void kernel_launch(void* const* d_in, const int* in_sizes, int n_in,
                              void* d_out, int out_size, void* d_ws, size_t ws_size,
                              hipStream_t stream)
{
    const float* P0 = (const float*)d_in[0];
    const float* P1 = (const float*)d_in[1];
    float* out = (float*)d_out;

    unsigned* dmin = (unsigned*)d_ws;                          // 2*NPTS u32 (128 KB)
    float4* Pt = (float4*)((char*)d_ws + 2 * NPTS * sizeof(unsigned)); // 2*NPTS float4 (512 KB), 16B-aligned

    // Init partial-min arrays to a huge float: 0x7F7F7F7F = 3.39e38 (> any real dist).
    hipMemsetAsync(dmin, 0x7F, (size_t)(2 * NPTS) * sizeof(unsigned), stream);

    prep_kernel<<<(2 * NPTS) / 256, 256, 0, stream>>>(P0, P1, Pt);

    dim3 grid(NATILES, NCHUNKS, 2);   // 16 x 32 x 2 = 1024 blocks
    chamfer_min_kernel<<<grid, BLOCK, 0, stream>>>(Pt, dmin);

    chamfer_reduce_kernel<<<1, 1024, 0, stream>>>(dmin, out);
}

// Round 7
// 47.679 us; speedup vs baseline: 3.7228x; 1.7001x over previous
//
#include <hip/hip_runtime.h>

// Chamfer (bidirectional 1-NN mean of squared distances), two [16384,3] fp32 clouds.
// Round-7: MFMA engine. d(i,j) tile computed by ONE v_mfma_f32_32x32x16_f16 via
// split-fp16 (x = xh + xl, each fp16; ~22 mantissa bits recovered):
//   K slots: 0..2  A=-2a_hi{x,y,z}  B=b_hi{x,y,z}
//            3..5  A=-2a_hi         B=b_lo
//            6..8  A=-2a_lo         B=b_hi
//            9,10  A={a2_hi,a2_lo}  B={1,1}
//            11,12 A={1,1}          B={b2_hi,b2_lo}
//            13..15 zero
//   => D[i][j] = a2 + b2 - 2 a.b + O(3e-3)  directly in fp32 accumulators.
// Layouts: A lane l holds row i=l&31, k=8*(l>>5)+e; B lane l holds col j=l&31,
// k=8*(l>>5)+e; C/D col=lane&31, row=(reg&3)+8*(reg>>2)+4*(lane>>5) (verified).
// Per wave: 1 A-tile (32 pts) held in 4 VGPRs, sweeps B-chunks staged in LDS
// ([half][pt] layout -> contiguous 16B/lane ds_read_b128, conflict-free).
// Row-min kept as 16 running registers; butterfly over 32 lanes at the end;
// atomicMin(uint) merge across the 8 B-splits. Separate reduce kernel (fused
// tails with __threadfence were the R2-R5 poison).

typedef _Float16 half8 __attribute__((ext_vector_type(8)));
typedef float floatx16 __attribute__((ext_vector_type(16)));

#define NPTS 16384
#define BLOCK 256
#define WAVES 4
#define TILE 32
#define APB (WAVES * TILE)            // 128 A-points per block
#define NBSPLIT 8
#define BSWEEP (NPTS / NBSPLIT)       // 2048 B-points per block
#define CHUNKB 512                    // B-points staged in LDS at a time
#define NSTAGE (BSWEEP / CHUNKB)      // 4
#define TPS (CHUNKB / TILE)           // 16 tiles per stage

union H8 { _Float16 h[8]; uint4 u; };

// Pack both clouds into A-format and B-format fragments (32 B/point each).
__global__ __launch_bounds__(256) void prep_kernel(
    const float* __restrict__ P0, const float* __restrict__ P1,
    uint4* __restrict__ Ap, uint4* __restrict__ Bp)
{
    const int i = blockIdx.x * 256 + threadIdx.x;      // 0..2*NPTS-1
    const float* P = (i < NPTS) ? P0 : P1;
    const int k = (i < NPTS) ? i : i - NPTS;
    const float x = P[k * 3 + 0], y = P[k * 3 + 1], z = P[k * 3 + 2];
    const float q2 = x * x + y * y + z * z;

    const _Float16 xh = (_Float16)x; const float xl = x - (float)xh;
    const _Float16 yh = (_Float16)y; const float yl = y - (float)yh;
    const _Float16 zh = (_Float16)z; const float zl = z - (float)zh;
    const _Float16 qh = (_Float16)q2; const float ql = q2 - (float)qh;
    const _Float16 one = (_Float16)1.0f, zero = (_Float16)0.0f;

    H8 a0, a1, b0, b1;
    a0.h[0] = (_Float16)(-2.0f * (float)xh);
    a0.h[1] = (_Float16)(-2.0f * (float)yh);
    a0.h[2] = (_Float16)(-2.0f * (float)zh);
    a0.h[3] = a0.h[0]; a0.h[4] = a0.h[1]; a0.h[5] = a0.h[2];
    a0.h[6] = (_Float16)(-2.0f * xl);
    a0.h[7] = (_Float16)(-2.0f * yl);
    a1.h[0] = (_Float16)(-2.0f * zl);
    a1.h[1] = qh; a1.h[2] = (_Float16)ql;
    a1.h[3] = one; a1.h[4] = one;
    a1.h[5] = zero; a1.h[6] = zero; a1.h[7] = zero;

    b0.h[0] = xh; b0.h[1] = yh; b0.h[2] = zh;
    b0.h[3] = (_Float16)xl; b0.h[4] = (_Float16)yl; b0.h[5] = (_Float16)zl;
    b0.h[6] = xh; b0.h[7] = yh;
    b1.h[0] = zh; b1.h[1] = one; b1.h[2] = one;
    b1.h[3] = qh; b1.h[4] = (_Float16)ql;
    b1.h[5] = zero; b1.h[6] = zero; b1.h[7] = zero;

    Ap[(size_t)i * 2 + 0] = a0.u; Ap[(size_t)i * 2 + 1] = a1.u;
    Bp[(size_t)i * 2 + 0] = b0.u; Bp[(size_t)i * 2 + 1] = b1.u;
}

__global__ __launch_bounds__(BLOCK, 4) void chamfer_mfma(
    const uint4* __restrict__ Ap, const uint4* __restrict__ Bp,
    unsigned* __restrict__ dmin_all)
{
    __shared__ uint4 sB[2][CHUNKB];   // [half][pt]: contiguous 16B/lane reads

    const int tid  = threadIdx.x;
    const int lane = tid & 63;
    const int wid  = tid >> 6;
    const int half = lane >> 5;
    const int lj   = lane & 31;

    const int dir = blockIdx.z;
    const uint4* Arole = Ap + (size_t)dir * NPTS * 2;
    const uint4* Brole = Bp + (size_t)(1 - dir) * NPTS * 2;
    unsigned* dmin = dmin_all + dir * NPTS;

    const int arow0 = blockIdx.x * APB + wid * TILE;

    // A fragment: held in 4 VGPRs for the whole kernel.
    const half8 af = *reinterpret_cast<const half8*>(
        &Arole[((size_t)(arow0 + lj)) * 2 + half]);

    float rmin[16];
#pragma unroll
    for (int r = 0; r < 16; ++r) rmin[r] = 3.0e38f;

    const int bbase = blockIdx.y * BSWEEP;

    for (int s = 0; s < NSTAGE; ++s) {
        __syncthreads();
        // Stage CHUNKB B-points: global [pt][half] -> LDS [half][pt].
        const uint4* src = &Brole[(size_t)(bbase + s * CHUNKB) * 2];
#pragma unroll
        for (int v = tid; v < 2 * CHUNKB; v += BLOCK) {
            sB[v & 1][v >> 1] = src[v];
        }
        __syncthreads();

        const uint4* myB = &sB[half][0];
#pragma unroll
        for (int t = 0; t < TPS; t += 2) {
            const half8 bf0 = *reinterpret_cast<const half8*>(&myB[t * TILE + lj]);
            const half8 bf1 = *reinterpret_cast<const half8*>(&myB[(t + 1) * TILE + lj]);
            floatx16 d0 = __builtin_amdgcn_mfma_f32_32x32x16_f16(af, bf0, (floatx16)(0.0f), 0, 0, 0);
            floatx16 d1 = __builtin_amdgcn_mfma_f32_32x32x16_f16(af, bf1, (floatx16)(0.0f), 0, 0, 0);
#pragma unroll
            for (int r = 0; r < 16; ++r)
                rmin[r] = fminf(fminf(d0[r], d1[r]), rmin[r]);   // v_min3_f32
        }
    }

    // Butterfly min over the 32 lanes that share the same 16 rows.
#pragma unroll
    for (int r = 0; r < 16; ++r) {
        float v = rmin[r];
        v = fminf(v, __shfl_xor(v, 1, 32));
        v = fminf(v, __shfl_xor(v, 2, 32));
        v = fminf(v, __shfl_xor(v, 4, 32));
        v = fminf(v, __shfl_xor(v, 8, 32));
        v = fminf(v, __shfl_xor(v, 16, 32));
        rmin[r] = v;
    }
    if (lj == 0) {
#pragma unroll
        for (int r = 0; r < 16; ++r) {
            const int row = (r & 3) + 8 * (r >> 2) + 4 * half;
            const float d = fmaxf(rmin[r], 0.0f);   // clamp (also keeps uint order valid)
            atomicMin(&dmin[arow0 + row], __float_as_uint(d));
        }
    }
}

__global__ __launch_bounds__(1024) void chamfer_reduce_kernel(
    const unsigned* __restrict__ dmin_all, float* __restrict__ out)
{
    __shared__ double sdata[1024];
    double s = 0.0;
    for (int i = threadIdx.x; i < 2 * NPTS; i += 1024)
        s += (double)__uint_as_float(dmin_all[i]);
    sdata[threadIdx.x] = s;
    __syncthreads();
    for (int off = 512; off > 0; off >>= 1) {
        if (threadIdx.x < off) sdata[threadIdx.x] += sdata[threadIdx.x + off];
        __syncthreads();
    }
    if (threadIdx.x == 0) out[0] = (float)(sdata[0] / (double)NPTS);
}

extern "C" void kernel_launch(void* const* d_in, const int* in_sizes, int n_in,
                              void* d_out, int out_size, void* d_ws, size_t ws_size,
                              hipStream_t stream)
{
    const float* P0 = (const float*)d_in[0];
    const float* P1 = (const float*)d_in[1];
    float* out = (float*)d_out;

    unsigned* dmin = (unsigned*)d_ws;                              // 128 KB
    uint4* Ap = (uint4*)((char*)d_ws + 2 * NPTS * sizeof(unsigned));      // 1 MB
    uint4* Bp = Ap + (size_t)2 * NPTS * 2;                                // 1 MB

    // dmin init: 0x7F7F7F7F = 3.39e38 > any real distance.
    hipMemsetAsync(dmin, 0x7F, (size_t)(2 * NPTS) * sizeof(unsigned), stream);

    prep_kernel<<<(2 * NPTS) / 256, 256, 0, stream>>>(P0, P1, Ap, Bp);

    dim3 grid(NPTS / APB, NBSPLIT, 2);   // 128 x 8 x 2 = 2048 blocks
    chamfer_mfma<<<grid, BLOCK, 0, stream>>>(Ap, Bp, dmin);

    chamfer_reduce_kernel<<<1, 1024, 0, stream>>>(dmin, out);
}

// Round 8
// 45.332 us; speedup vs baseline: 3.9156x; 1.0518x over previous
//
#include <hip/hip_runtime.h>

// Chamfer (bidirectional 1-NN mean of squared distances), two [16384,3] fp32 clouds.
// Round-8: identical compute to round-7 (split-fp16 MFMA, verified absmax 0.0).
// Single change: the hipMemsetAsync(dmin) node cost ~39us PER GRAPH REPLAY
// (rocclr fillBufferAligned dominated the timed dispatches at 131KB!). The dmin
// init is now folded into prep_kernel (2*NPTS threads map 1:1 onto dmin), and the
// memset is gone. Stream order guarantees init happens before chamfer_mfma's
// atomicMin merges.
//
// MFMA formulation (one v_mfma_f32_32x32x16_f16 per 32x32 distance tile):
//   x = xh + xl (split fp16). K slots:
//     0..2  A=-2a_hi{x,y,z}  B=b_hi{x,y,z}
//     3..5  A=-2a_hi         B=b_lo
//     6..8  A=-2a_lo         B=b_hi
//     9,10  A={a2_hi,a2_lo}  B={1,1}
//     11,12 A={1,1}          B={b2_hi,b2_lo}
//     13..15 zero
//   => D[i][j] = a2 + b2 - 2 a.b + O(3e-3), fp32 accumulators.

typedef _Float16 half8 __attribute__((ext_vector_type(8)));
typedef float floatx16 __attribute__((ext_vector_type(16)));

#define NPTS 16384
#define BLOCK 256
#define WAVES 4
#define TILE 32
#define APB (WAVES * TILE)            // 128 A-points per block
#define NBSPLIT 8
#define BSWEEP (NPTS / NBSPLIT)       // 2048 B-points per block
#define CHUNKB 512                    // B-points staged in LDS at a time
#define NSTAGE (BSWEEP / CHUNKB)      // 4
#define TPS (CHUNKB / TILE)           // 16 tiles per stage

union H8 { _Float16 h[8]; uint4 u; };

// Pack both clouds into A-format and B-format fragments (32 B/point each),
// and initialize the partial-min array (replaces the 39us memset node).
__global__ __launch_bounds__(256) void prep_kernel(
    const float* __restrict__ P0, const float* __restrict__ P1,
    uint4* __restrict__ Ap, uint4* __restrict__ Bp,
    unsigned* __restrict__ dmin_all)
{
    const int i = blockIdx.x * 256 + threadIdx.x;      // 0..2*NPTS-1
    dmin_all[i] = 0x7F7F7F7Fu;                         // 3.39e38 > any real distance

    const float* P = (i < NPTS) ? P0 : P1;
    const int k = (i < NPTS) ? i : i - NPTS;
    const float x = P[k * 3 + 0], y = P[k * 3 + 1], z = P[k * 3 + 2];
    const float q2 = x * x + y * y + z * z;

    const _Float16 xh = (_Float16)x; const float xl = x - (float)xh;
    const _Float16 yh = (_Float16)y; const float yl = y - (float)yh;
    const _Float16 zh = (_Float16)z; const float zl = z - (float)zh;
    const _Float16 qh = (_Float16)q2; const float ql = q2 - (float)qh;
    const _Float16 one = (_Float16)1.0f, zero = (_Float16)0.0f;

    H8 a0, a1, b0, b1;
    a0.h[0] = (_Float16)(-2.0f * (float)xh);
    a0.h[1] = (_Float16)(-2.0f * (float)yh);
    a0.h[2] = (_Float16)(-2.0f * (float)zh);
    a0.h[3] = a0.h[0]; a0.h[4] = a0.h[1]; a0.h[5] = a0.h[2];
    a0.h[6] = (_Float16)(-2.0f * xl);
    a0.h[7] = (_Float16)(-2.0f * yl);
    a1.h[0] = (_Float16)(-2.0f * zl);
    a1.h[1] = qh; a1.h[2] = (_Float16)ql;
    a1.h[3] = one; a1.h[4] = one;
    a1.h[5] = zero; a1.h[6] = zero; a1.h[7] = zero;

    b0.h[0] = xh; b0.h[1] = yh; b0.h[2] = zh;
    b0.h[3] = (_Float16)xl; b0.h[4] = (_Float16)yl; b0.h[5] = (_Float16)zl;
    b0.h[6] = xh; b0.h[7] = yh;
    b1.h[0] = zh; b1.h[1] = one; b1.h[2] = one;
    b1.h[3] = qh; b1.h[4] = (_Float16)ql;
    b1.h[5] = zero; b1.h[6] = zero; b1.h[7] = zero;

    Ap[(size_t)i * 2 + 0] = a0.u; Ap[(size_t)i * 2 + 1] = a1.u;
    Bp[(size_t)i * 2 + 0] = b0.u; Bp[(size_t)i * 2 + 1] = b1.u;
}

__global__ __launch_bounds__(BLOCK, 4) void chamfer_mfma(
    const uint4* __restrict__ Ap, const uint4* __restrict__ Bp,
    unsigned* __restrict__ dmin_all)
{
    __shared__ uint4 sB[2][CHUNKB];   // [half][pt]: contiguous 16B/lane reads

    const int tid  = threadIdx.x;
    const int lane = tid & 63;
    const int wid  = tid >> 6;
    const int half = lane >> 5;
    const int lj   = lane & 31;

    const int dir = blockIdx.z;
    const uint4* Arole = Ap + (size_t)dir * NPTS * 2;
    const uint4* Brole = Bp + (size_t)(1 - dir) * NPTS * 2;
    unsigned* dmin = dmin_all + dir * NPTS;

    const int arow0 = blockIdx.x * APB + wid * TILE;

    // A fragment: held in 4 VGPRs for the whole kernel.
    const half8 af = *reinterpret_cast<const half8*>(
        &Arole[((size_t)(arow0 + lj)) * 2 + half]);

    float rmin[16];
#pragma unroll
    for (int r = 0; r < 16; ++r) rmin[r] = 3.0e38f;

    const int bbase = blockIdx.y * BSWEEP;

    for (int s = 0; s < NSTAGE; ++s) {
        __syncthreads();
        // Stage CHUNKB B-points: global [pt][half] -> LDS [half][pt].
        const uint4* src = &Brole[(size_t)(bbase + s * CHUNKB) * 2];
#pragma unroll
        for (int v = tid; v < 2 * CHUNKB; v += BLOCK) {
            sB[v & 1][v >> 1] = src[v];
        }
        __syncthreads();

        const uint4* myB = &sB[half][0];
#pragma unroll
        for (int t = 0; t < TPS; t += 2) {
            const half8 bf0 = *reinterpret_cast<const half8*>(&myB[t * TILE + lj]);
            const half8 bf1 = *reinterpret_cast<const half8*>(&myB[(t + 1) * TILE + lj]);
            floatx16 d0 = __builtin_amdgcn_mfma_f32_32x32x16_f16(af, bf0, (floatx16)(0.0f), 0, 0, 0);
            floatx16 d1 = __builtin_amdgcn_mfma_f32_32x32x16_f16(af, bf1, (floatx16)(0.0f), 0, 0, 0);
#pragma unroll
            for (int r = 0; r < 16; ++r)
                rmin[r] = fminf(fminf(d0[r], d1[r]), rmin[r]);   // v_min3_f32
        }
    }

    // Butterfly min over the 32 lanes that share the same 16 rows.
#pragma unroll
    for (int r = 0; r < 16; ++r) {
        float v = rmin[r];
        v = fminf(v, __shfl_xor(v, 1, 32));
        v = fminf(v, __shfl_xor(v, 2, 32));
        v = fminf(v, __shfl_xor(v, 4, 32));
        v = fminf(v, __shfl_xor(v, 8, 32));
        v = fminf(v, __shfl_xor(v, 16, 32));
        rmin[r] = v;
    }
    if (lj == 0) {
#pragma unroll
        for (int r = 0; r < 16; ++r) {
            const int row = (r & 3) + 8 * (r >> 2) + 4 * half;
            const float d = fmaxf(rmin[r], 0.0f);   // clamp (also keeps uint order valid)
            atomicMin(&dmin[arow0 + row], __float_as_uint(d));
        }
    }
}

__global__ __launch_bounds__(1024) void chamfer_reduce_kernel(
    const unsigned* __restrict__ dmin_all, float* __restrict__ out)
{
    __shared__ double sdata[1024];
    double s = 0.0;
    for (int i = threadIdx.x; i < 2 * NPTS; i += 1024)
        s += (double)__uint_as_float(dmin_all[i]);
    sdata[threadIdx.x] = s;
    __syncthreads();
    for (int off = 512; off > 0; off >>= 1) {
        if (threadIdx.x < off) sdata[threadIdx.x] += sdata[threadIdx.x + off];
        __syncthreads();
    }
    if (threadIdx.x == 0) out[0] = (float)(sdata[0] / (double)NPTS);
}

extern "C" void kernel_launch(void* const* d_in, const int* in_sizes, int n_in,
                              void* d_out, int out_size, void* d_ws, size_t ws_size,
                              hipStream_t stream)
{
    const float* P0 = (const float*)d_in[0];
    const float* P1 = (const float*)d_in[1];
    float* out = (float*)d_out;

    unsigned* dmin = (unsigned*)d_ws;                                     // 128 KB
    uint4* Ap = (uint4*)((char*)d_ws + 2 * NPTS * sizeof(unsigned));      // 1 MB
    uint4* Bp = Ap + (size_t)2 * NPTS * 2;                                // 1 MB

    prep_kernel<<<(2 * NPTS) / 256, 256, 0, stream>>>(P0, P1, Ap, Bp, dmin);

    dim3 grid(NPTS / APB, NBSPLIT, 2);   // 128 x 8 x 2 = 2048 blocks
    chamfer_mfma<<<grid, BLOCK, 0, stream>>>(Ap, Bp, dmin);

    chamfer_reduce_kernel<<<1, 1024, 0, stream>>>(dmin, out);
}

// Round 9
// 43.777 us; speedup vs baseline: 4.0547x; 1.0355x over previous
//
#include <hip/hip_runtime.h>

// Chamfer (bidirectional 1-NN mean of squared distances), two [16384,3] fp32 clouds.
// Round-9: same verified split-fp16 MFMA numerics as R7/R8 (absmax 0.0). R8 pipe
// accounting: chamfer_mfma ~36us = LDS pipe ~20us (1 ds_read_b128/MFMA + staging)
// + VALU ~22us (min3 13.7 + butterfly tail 8.5) + MFMA 6.9, poorly overlapped.
// Changes:
//  - 2 A-fragments per wave (64 A-rows): each B ds_read feeds 2 MFMAs -> LDS
//    read+write traffic halved (~7us).
//  - NBSPLIT 8->4: half the waves -> butterfly tail 8.5->4.2us.
//  - __launch_bounds__(256,2): ~120 live VGPRs (4 d-tuples, 2 rmin sets), avoid spill.
//
// MFMA formulation (one v_mfma_f32_32x32x16_f16 per 32x32 distance tile):
//   x = xh + xl (split fp16). K slots:
//     0..2 A=-2a_hi B=b_hi | 3..5 A=-2a_hi B=b_lo | 6..8 A=-2a_lo B=b_hi
//     9,10 A={a2_hi,a2_lo} B={1,1} | 11,12 A={1,1} B={b2_hi,b2_lo} | 13..15 zero
//   => D[i][j] = a2 + b2 - 2 a.b + O(3e-3), fp32 accumulators.

typedef _Float16 half8 __attribute__((ext_vector_type(8)));
typedef float floatx16 __attribute__((ext_vector_type(16)));

#define NPTS 16384
#define BLOCK 256
#define WAVES 4
#define TILE 32
#define ROWSW (2 * TILE)              // 64 A-rows per wave (2 fragments)
#define APB (WAVES * ROWSW)           // 256 A-points per block
#define NBSPLIT 4
#define BSWEEP (NPTS / NBSPLIT)       // 4096 B-points per block
#define CHUNKB 512                    // B-points staged in LDS at a time
#define NSTAGE (BSWEEP / CHUNKB)      // 8
#define TPS (CHUNKB / TILE)           // 16 tiles per stage

union H8 { _Float16 h[8]; uint4 u; };

// Pack both clouds into A-format and B-format fragments (32 B/point each),
// and initialize the partial-min array (memset node costs ~2.4us in-graph).
__global__ __launch_bounds__(256) void prep_kernel(
    const float* __restrict__ P0, const float* __restrict__ P1,
    uint4* __restrict__ Ap, uint4* __restrict__ Bp,
    unsigned* __restrict__ dmin_all)
{
    const int i = blockIdx.x * 256 + threadIdx.x;      // 0..2*NPTS-1
    dmin_all[i] = 0x7F7F7F7Fu;                         // 3.39e38 > any real distance

    const float* P = (i < NPTS) ? P0 : P1;
    const int k = (i < NPTS) ? i : i - NPTS;
    const float x = P[k * 3 + 0], y = P[k * 3 + 1], z = P[k * 3 + 2];
    const float q2 = x * x + y * y + z * z;

    const _Float16 xh = (_Float16)x; const float xl = x - (float)xh;
    const _Float16 yh = (_Float16)y; const float yl = y - (float)yh;
    const _Float16 zh = (_Float16)z; const float zl = z - (float)zh;
    const _Float16 qh = (_Float16)q2; const float ql = q2 - (float)qh;
    const _Float16 one = (_Float16)1.0f, zero = (_Float16)0.0f;

    H8 a0, a1, b0, b1;
    a0.h[0] = (_Float16)(-2.0f * (float)xh);
    a0.h[1] = (_Float16)(-2.0f * (float)yh);
    a0.h[2] = (_Float16)(-2.0f * (float)zh);
    a0.h[3] = a0.h[0]; a0.h[4] = a0.h[1]; a0.h[5] = a0.h[2];
    a0.h[6] = (_Float16)(-2.0f * xl);
    a0.h[7] = (_Float16)(-2.0f * yl);
    a1.h[0] = (_Float16)(-2.0f * zl);
    a1.h[1] = qh; a1.h[2] = (_Float16)ql;
    a1.h[3] = one; a1.h[4] = one;
    a1.h[5] = zero; a1.h[6] = zero; a1.h[7] = zero;

    b0.h[0] = xh; b0.h[1] = yh; b0.h[2] = zh;
    b0.h[3] = (_Float16)xl; b0.h[4] = (_Float16)yl; b0.h[5] = (_Float16)zl;
    b0.h[6] = xh; b0.h[7] = yh;
    b1.h[0] = zh; b1.h[1] = one; b1.h[2] = one;
    b1.h[3] = qh; b1.h[4] = (_Float16)ql;
    b1.h[5] = zero; b1.h[6] = zero; b1.h[7] = zero;

    Ap[(size_t)i * 2 + 0] = a0.u; Ap[(size_t)i * 2 + 1] = a1.u;
    Bp[(size_t)i * 2 + 0] = b0.u; Bp[(size_t)i * 2 + 1] = b1.u;
}

__global__ __launch_bounds__(BLOCK, 2) void chamfer_mfma(
    const uint4* __restrict__ Ap, const uint4* __restrict__ Bp,
    unsigned* __restrict__ dmin_all)
{
    __shared__ uint4 sB[2][CHUNKB];   // [half][pt]: contiguous 16B/lane reads

    const int tid  = threadIdx.x;
    const int lane = tid & 63;
    const int wid  = tid >> 6;
    const int half = lane >> 5;
    const int lj   = lane & 31;

    const int dir = blockIdx.z;
    const uint4* Arole = Ap + (size_t)dir * NPTS * 2;
    const uint4* Brole = Bp + (size_t)(1 - dir) * NPTS * 2;
    unsigned* dmin = dmin_all + dir * NPTS;

    const int arow0 = blockIdx.x * APB + wid * ROWSW;

    // Two A fragments per wave (rows arow0+lj and arow0+32+lj), resident in 8 VGPRs.
    const half8 af0 = *reinterpret_cast<const half8*>(
        &Arole[((size_t)(arow0 + lj)) * 2 + half]);
    const half8 af1 = *reinterpret_cast<const half8*>(
        &Arole[((size_t)(arow0 + 32 + lj)) * 2 + half]);

    float rmin0[16], rmin1[16];
#pragma unroll
    for (int r = 0; r < 16; ++r) { rmin0[r] = 3.0e38f; rmin1[r] = 3.0e38f; }

    const int bbase = blockIdx.y * BSWEEP;

    for (int s = 0; s < NSTAGE; ++s) {
        __syncthreads();
        // Stage CHUNKB B-points: global [pt][half] -> LDS [half][pt].
        const uint4* src = &Brole[(size_t)(bbase + s * CHUNKB) * 2];
#pragma unroll
        for (int v = tid; v < 2 * CHUNKB; v += BLOCK) {
            sB[v & 1][v >> 1] = src[v];
        }
        __syncthreads();

        const uint4* myB = &sB[half][0];
#pragma unroll 4
        for (int t = 0; t < TPS; t += 2) {
            // Each B fragment feeds TWO MFMAs (af0, af1): LDS reads halved per MFMA.
            const half8 bf0 = *reinterpret_cast<const half8*>(&myB[t * TILE + lj]);
            const half8 bf1 = *reinterpret_cast<const half8*>(&myB[(t + 1) * TILE + lj]);
            floatx16 d00 = __builtin_amdgcn_mfma_f32_32x32x16_f16(af0, bf0, (floatx16)(0.0f), 0, 0, 0);
            floatx16 d01 = __builtin_amdgcn_mfma_f32_32x32x16_f16(af0, bf1, (floatx16)(0.0f), 0, 0, 0);
#pragma unroll
            for (int r = 0; r < 16; ++r)
                rmin0[r] = fminf(fminf(d00[r], d01[r]), rmin0[r]);   // v_min3_f32
            floatx16 d10 = __builtin_amdgcn_mfma_f32_32x32x16_f16(af1, bf0, (floatx16)(0.0f), 0, 0, 0);
            floatx16 d11 = __builtin_amdgcn_mfma_f32_32x32x16_f16(af1, bf1, (floatx16)(0.0f), 0, 0, 0);
#pragma unroll
            for (int r = 0; r < 16; ++r)
                rmin1[r] = fminf(fminf(d10[r], d11[r]), rmin1[r]);
        }
    }

    // Butterfly min over the 32 lanes sharing each row set, then merge.
#pragma unroll
    for (int r = 0; r < 16; ++r) {
        float v0 = rmin0[r];
        v0 = fminf(v0, __shfl_xor(v0, 1, 32));
        v0 = fminf(v0, __shfl_xor(v0, 2, 32));
        v0 = fminf(v0, __shfl_xor(v0, 4, 32));
        v0 = fminf(v0, __shfl_xor(v0, 8, 32));
        v0 = fminf(v0, __shfl_xor(v0, 16, 32));
        rmin0[r] = v0;
        float v1 = rmin1[r];
        v1 = fminf(v1, __shfl_xor(v1, 1, 32));
        v1 = fminf(v1, __shfl_xor(v1, 2, 32));
        v1 = fminf(v1, __shfl_xor(v1, 4, 32));
        v1 = fminf(v1, __shfl_xor(v1, 8, 32));
        v1 = fminf(v1, __shfl_xor(v1, 16, 32));
        rmin1[r] = v1;
    }
    if (lj == 0) {
#pragma unroll
        for (int r = 0; r < 16; ++r) {
            const int row = (r & 3) + 8 * (r >> 2) + 4 * half;
            atomicMin(&dmin[arow0 + row],
                      __float_as_uint(fmaxf(rmin0[r], 0.0f)));
            atomicMin(&dmin[arow0 + 32 + row],
                      __float_as_uint(fmaxf(rmin1[r], 0.0f)));
        }
    }
}

__global__ __launch_bounds__(1024) void chamfer_reduce_kernel(
    const unsigned* __restrict__ dmin_all, float* __restrict__ out)
{
    __shared__ double sdata[1024];
    double s = 0.0;
    for (int i = threadIdx.x; i < 2 * NPTS; i += 1024)
        s += (double)__uint_as_float(dmin_all[i]);
    sdata[threadIdx.x] = s;
    __syncthreads();
    for (int off = 512; off > 0; off >>= 1) {
        if (threadIdx.x < off) sdata[threadIdx.x] += sdata[threadIdx.x + off];
        __syncthreads();
    }
    if (threadIdx.x == 0) out[0] = (float)(sdata[0] / (double)NPTS);
}

extern "C" void kernel_launch(void* const* d_in, const int* in_sizes, int n_in,
                              void* d_out, int out_size, void* d_ws, size_t ws_size,
                              hipStream_t stream)
{
    const float* P0 = (const float*)d_in[0];
    const float* P1 = (const float*)d_in[1];
    float* out = (float*)d_out;

    unsigned* dmin = (unsigned*)d_ws;                                     // 128 KB
    uint4* Ap = (uint4*)((char*)d_ws + 2 * NPTS * sizeof(unsigned));      // 1 MB
    uint4* Bp = Ap + (size_t)2 * NPTS * 2;                                // 1 MB

    prep_kernel<<<(2 * NPTS) / 256, 256, 0, stream>>>(P0, P1, Ap, Bp, dmin);

    dim3 grid(NPTS / APB, NBSPLIT, 2);   // 64 x 4 x 2 = 512 blocks
    chamfer_mfma<<<grid, BLOCK, 0, stream>>>(Ap, Bp, dmin);

    chamfer_reduce_kernel<<<1, 1024, 0, stream>>>(dmin, out);
}